// Round 12
// baseline (320.733 us; speedup 1.0000x reference)
//
// rev r27 — r26 with the scan dispatch FOLDED into the fat kernel (6 -> 5
// dispatches). Two rounds of budget arithmetic show ~14 µs/dispatch of
// gap/overhead (r21: 9 disp = 126+184 ≈ 310; r26: 6 disp = 84+206 ≈ 290) —
// dispatch count is a first-class cost. gemm_scan_fill roles:
//   [0,sb): r26-proven lookback scan + threadfence + done-counter bump
//   [sb,sb+gwb): layer-1 MFMA GEMM (depends only on hist's W tables)
//   rest: fill — polls done==sb (scan blocks dispatched first -> always
//   resident before any fill spins; fill depends only on scan => no deadlock)
// zero kernel extended to clear the done word. hist/fused/agg2 byte-identical
// to r26 (replay-proven).
// r24: 297.1, r25: 312.9, r26: 289.7 (fused=72). Predict ~272.
#include <hip/hip_runtime.h>

typedef unsigned short u16;
typedef unsigned int   u32;
typedef __attribute__((ext_vector_type(8))) short bh8;   // 8 bf16 (4 VGPRs)
typedef __attribute__((ext_vector_type(4))) float fx4;   // MFMA accumulator

#define SCAN_FLAG 0x40000000

__device__ __forceinline__ float b2f(u16 h){ return __uint_as_float(((u32)h) << 16); }
__device__ __forceinline__ u16   f2b(float f){
  u32 u = __float_as_uint(f);
  u32 r = u + 0x7FFFu + ((u >> 16) & 1u);   // round-to-nearest-even
  return (u16)(r >> 16);
}
__device__ __forceinline__ float lo16(u32 w){ return b2f((u16)(w & 0xFFFFu)); }
__device__ __forceinline__ float hi16(u32 w){ return b2f((u16)(w >> 16)); }

// ---- A: zero cnt + pub + sdone (pure, ~2 µs) ----
__global__ void r27_zero(int* __restrict__ cnt, int n1, int* __restrict__ pub){
  int g = (int)blockIdx.x*256 + threadIdx.x;
  if (g < n1) cnt[g] = 0;
  else if (g < n1 + 257) pub[g - n1] = 0;   // pub[0..255] + sdone at pub[256]
}

// ---- B: W^T bf16 hi/lo tables (blocks 0..15), ws/wd (block 16),
// histogram 8 edges/thread (blocks 17..) — prep rides free under hist.
__global__ void r27_hist_prep(const int* __restrict__ ei, int E, int Ep, int* cnt,
                              u16* __restrict__ rank,
                              const float* __restrict__ W1, const float* __restrict__ as1,
                              const float* __restrict__ ad1,
                              const float* __restrict__ W2, const float* __restrict__ as2,
                              const float* __restrict__ ad2,
                              u16* __restrict__ w1H, u16* __restrict__ w1L,
                              u16* __restrict__ w2H, u16* __restrict__ w2L,
                              float* __restrict__ ws1, float* __restrict__ wd1,
                              float* __restrict__ ws2, float* __restrict__ wd2){
  int b = blockIdx.x;
  int t = threadIdx.x;
  if (b < 16){
    const float* W = (b < 8) ? W1 : W2;
    u16* HT = (b < 8) ? w1H : w2H;
    u16* LT = (b < 8) ? w1L : w2L;
    int n0 = (b & 7) * 16;
    #pragma unroll
    for (int it = 0; it < 8; ++it){
      int idx = it*256 + t;              // 0..2047
      int nn = n0 + (idx >> 7);
      int k = idx & 127;
      float w = W[(size_t)k*128 + nn];
      u16 h = f2b(w);
      HT[(size_t)nn*128 + k] = h;
      LT[(size_t)nn*128 + k] = f2b(w - b2f(h));
    }
    return;
  }
  if (b == 16){
    int which = t >> 6;                  // 0:ws1 1:wd1 2:ws2 3:wd2
    const float* W   = (which < 2) ? W1 : W2;
    const float* att = (which == 0) ? as1 : (which == 1) ? ad1 : (which == 2) ? as2 : ad2;
    float* outv      = (which == 0) ? ws1 : (which == 1) ? wd1 : (which == 2) ? ws2 : wd2;
    int k0 = (t & 63) * 2;
    #pragma unroll
    for (int kk = 0; kk < 2; ++kk){
      int k = k0 + kk;
      float s = 0.f;
      for (int c = 0; c < 128; ++c) s = fmaf(W[(size_t)k*128 + c], att[c], s);
      outv[k] = s;
    }
    return;
  }
  int g0 = (b - 17)*2048 + t;
  #pragma unroll
  for (int i = 0; i < 8; ++i){
    int g = g0 + i*256;
    if (g < Ep){
      int dst = (g < E) ? ei[E + g] : (g - E);
      int r = atomicAdd(&cnt[dst], 1);
      rank[g] = (u16)r;
    }
  }
}

// ---------------- MFMA bf16 GEMM, one wave = 16 rows, LDS-free ---------------
__device__ __forceinline__ void gemm16_wave(
    const float* __restrict__ X, const u16* __restrict__ wH, const u16* __restrict__ wL,
    const float* __restrict__ wsv, const float* __restrict__ wdv,
    u16* __restrict__ HB, float* __restrict__ AS, float* __restrict__ AD,
    int nrows, int w, int lane)
{
  int r0 = w * 16;
  if (r0 >= nrows) return;
  int rloc = lane & 15;
  int q    = lane >> 4;                   // k-chunk 0..3 within a K=32 step
  int myrow = r0 + rloc;
  bool act = (myrow < nrows);
  int rsafe = act ? myrow : (nrows - 1);

  fx4 acc[8] = {};                        // 8 col-frags x 4 f32
  float ds = 0.f, dd = 0.f;

  const u16* wHrow = wH + (size_t)rloc * 128;
  const u16* wLrow = wL + (size_t)rloc * 128;

  #pragma unroll
  for (int kk = 0; kk < 4; ++kk){
    int kbase = kk*32 + q*8;
    const float* xp = X + (size_t)rsafe*128 + kbase;
    float4 xa = *(const float4*)xp;
    float4 xb = *(const float4*)(xp + 4);
    float xv[8] = {xa.x, xa.y, xa.z, xa.w, xb.x, xb.y, xb.z, xb.w};
    if (!act){
      #pragma unroll
      for (int i = 0; i < 8; ++i) xv[i] = 0.f;
    }
    const float* sp = wsv + kbase;
    const float* dp = wdv + kbase;
    bh8 xh, xl;
    #pragma unroll
    for (int i = 0; i < 8; ++i){
      ds = fmaf(xv[i], sp[i], ds);        // exact f32 logit path: X@(W@att)
      dd = fmaf(xv[i], dp[i], dd);
      u16 h = f2b(xv[i]);
      xh[i] = (short)h;
      xl[i] = (short)f2b(xv[i] - b2f(h)); // hi/lo split: ~2^-17 rel error
    }
    #pragma unroll
    for (int cf = 0; cf < 8; ++cf){
      bh8 wh = *(const bh8*)(wHrow + (size_t)cf*2048 + kbase);
      bh8 wl = *(const bh8*)(wLrow + (size_t)cf*2048 + kbase);
      acc[cf] = __builtin_amdgcn_mfma_f32_16x16x32_bf16(wh, xh, acc[cf], 0, 0, 0);
      acc[cf] = __builtin_amdgcn_mfma_f32_16x16x32_bf16(wl, xh, acc[cf], 0, 0, 0);
      acc[cf] = __builtin_amdgcn_mfma_f32_16x16x32_bf16(wh, xl, acc[cf], 0, 0, 0);
    }
  }
  ds += __shfl_xor(ds, 16); ds += __shfl_xor(ds, 32);
  dd += __shfl_xor(dd, 16); dd += __shfl_xor(dd, 32);
  if (act && q == 0){ AS[myrow] = ds; AD[myrow] = dd; }
  if (act){
    u16* hrow = HB + (size_t)myrow*128 + q*4;
    #pragma unroll
    for (int cf = 0; cf < 8; ++cf){
      uint2 pb;
      pb.x = (u32)f2b(acc[cf][0]) | ((u32)f2b(acc[cf][1]) << 16);
      pb.y = (u32)f2b(acc[cf][2]) | ((u32)f2b(acc[cf][3]) << 16);
      *(uint2*)(hrow + cf*16) = pb;       // 4 consecutive bf16 cols, 8B aligned
    }
  }
}

// ---- C: FAT — scan role [0,sb), layer-1 MFMA GEMM [sb,sb+gwb), fill rest.
// Fill polls sdone (scan blocks dispatched first -> no deadlock).
__global__ __launch_bounds__(256)
void r27_gemm_scan_fill(const float* __restrict__ X,
                        const u16* __restrict__ wH, const u16* __restrict__ wL,
                        const float* __restrict__ wsv, const float* __restrict__ wdv,
                        u16* __restrict__ HB, float* __restrict__ AS, float* __restrict__ AD,
                        int nrows, int sb, int gemmBlocks,
                        const int* __restrict__ ei, int E, int Ep,
                        const int* __restrict__ cnt, int n1,
                        int* __restrict__ offs, int* __restrict__ pub,
                        const u16* __restrict__ rank, u16* __restrict__ csr){
  __shared__ int tmp[256];
  __shared__ int red[256];
  int t = threadIdx.x;
  int b = (int)blockIdx.x;
  int* sdone = pub + 256;

  if (b < sb){
    // ---- scan role (r26-proven lookback) ----
    int g = b*256 + t;
    int v = (g < n1) ? cnt[g] : 0;
    tmp[t] = v; __syncthreads();
    for (int off = 1; off < 256; off <<= 1){
      int u = (t >= off) ? tmp[t - off] : 0;
      __syncthreads();
      tmp[t] += u;
      __syncthreads();
    }
    int incl = tmp[t];
    if (t == 255) atomicExch(&pub[b], tmp[255] | SCAN_FLAG);
    int val = 0;
    if (t < b){
      int p;
      do { p = atomicAdd(&pub[t], 0); } while (!(p & SCAN_FLAG));
      val = p & ~SCAN_FLAG;
    }
    red[t] = val; __syncthreads();
    for (int off = 128; off >= 1; off >>= 1){
      if (t < off) red[t] += red[t + off];
      __syncthreads();
    }
    int add = red[0];
    if (g < n1) offs[g] = add + incl - v;  // exclusive prefix
    __syncthreads();
    if (t == 0){ __threadfence(); atomicAdd(sdone, 1); }
    return;
  }
  if (b < sb + gemmBlocks){
    // ---- gemm role (needs only W tables from hist_prep) ----
    int w = (b - sb)*4 + (t >> 6);
    gemm16_wave(X, wH, wL, wsv, wdv, HB, AS, AD, nrows, w, t & 63);
    return;
  }
  // ---- fill role: wait for scan, then atomic-free scatter ----
  if (t == 0){
    while (atomicAdd(sdone, 0) < sb) { }
    __threadfence();
  }
  __syncthreads();
  int g0 = (b - sb - gemmBlocks)*1024 + t;
  #pragma unroll
  for (int i = 0; i < 4; ++i){
    int g = g0 + i*256;
    if (g < Ep){
      int src, dst;
      if (g < E){ src = ei[g]; dst = ei[E + g]; } else { src = g - E; dst = g - E; }
      csr[offs[dst] + (int)rank[g]] = (u16)src;
    }
  }
}

// ---- D: FUSED agg1 + gemm2 (r24/r26 byte-identical). 16 waves = 16 nodes.
__global__ __launch_bounds__(1024)
void r27_fused(const u16* __restrict__ HB, const float* __restrict__ AS,
               const float* __restrict__ AD,
               const int* __restrict__ offs, const u16* __restrict__ csr,
               const float* __restrict__ bias,
               const float* __restrict__ gamma_, const float* __restrict__ beta_,
               const float* __restrict__ mean_, const float* __restrict__ var_,
               const u16* __restrict__ w2H, const u16* __restrict__ w2L,
               const float* __restrict__ ws2, const float* __restrict__ wd2,
               u16* __restrict__ HB2, float* __restrict__ AS2, float* __restrict__ AD2,
               int n){
  __shared__ float xs[16*132];           // 16 rows, stride 132 (bank-spread)
  int tid  = threadIdx.x;
  int w    = tid >> 6;                   // wave 0..15 = node slot
  int lane = tid & 63;
  int wid  = (int)blockIdx.x*16 + w;
  bool validNode = (wid < n);
  int h  = lane >> 5;
  int c4 = (lane & 31) * 4;
  float a0 = 0.f, a1 = 0.f, a2 = 0.f, a3 = 0.f;

  if (validNode){
    int beg = offs[wid], end = offs[wid+1];
    int deg = end - beg;
    float ad = AD[wid];
    if (deg <= 64){
      int   my_s = 0;
      float my_e = -3.0e38f;
      bool act = (lane < deg);
      if (act){
        my_s = (int)csr[beg + lane];
        float e = AS[my_s] + ad;
        my_e = (e > 0.f) ? e : 0.2f*e;
      }
      float m = my_e;
      #pragma unroll
      for (int off = 32; off >= 1; off >>= 1) m = fmaxf(m, __shfl_xor(m, off));
      float pz = act ? __expf(my_e - m) : 0.f;
      float den = pz;
      #pragma unroll
      for (int off = 32; off >= 1; off >>= 1) den += __shfl_xor(den, off);
      float my_al = pz / (den + 1e-16f);

      int npair = (deg + 1) >> 1;
      int k = 0;
      for (; k + 4 <= npair; k += 4){
        int j0 = 2*k + h, j1 = j0 + 2, j2 = j0 + 4, j3 = j0 + 6;
        int   s0 = __shfl(my_s, j0),  s1 = __shfl(my_s, j1);
        int   s2 = __shfl(my_s, j2),  s3 = __shfl(my_s, j3);
        float l0 = __shfl(my_al, j0), l1 = __shfl(my_al, j1);
        float l2 = __shfl(my_al, j2), l3 = __shfl(my_al, j3);
        uint2 q0 = *(const uint2*)&HB[(size_t)s0*128 + c4];
        uint2 q1 = *(const uint2*)&HB[(size_t)s1*128 + c4];
        uint2 q2 = *(const uint2*)&HB[(size_t)s2*128 + c4];
        uint2 q3 = *(const uint2*)&HB[(size_t)s3*128 + c4];
        a0 = fmaf(l0, lo16(q0.x), a0); a1 = fmaf(l0, hi16(q0.x), a1);
        a2 = fmaf(l0, lo16(q0.y), a2); a3 = fmaf(l0, hi16(q0.y), a3);
        a0 = fmaf(l1, lo16(q1.x), a0); a1 = fmaf(l1, hi16(q1.x), a1);
        a2 = fmaf(l1, lo16(q1.y), a2); a3 = fmaf(l1, hi16(q1.y), a3);
        a0 = fmaf(l2, lo16(q2.x), a0); a1 = fmaf(l2, hi16(q2.x), a1);
        a2 = fmaf(l2, lo16(q2.y), a2); a3 = fmaf(l2, hi16(q2.y), a3);
        a0 = fmaf(l3, lo16(q3.x), a0); a1 = fmaf(l3, hi16(q3.x), a1);
        a2 = fmaf(l3, lo16(q3.y), a2); a3 = fmaf(l3, hi16(q3.y), a3);
      }
      for (; k < npair; ++k){
        int j = 2*k + h;
        int   s = __shfl(my_s, j);
        float l = __shfl(my_al, j);
        uint2 q = *(const uint2*)&HB[(size_t)s*128 + c4];
        a0 = fmaf(l, lo16(q.x), a0); a1 = fmaf(l, hi16(q.x), a1);
        a2 = fmaf(l, lo16(q.y), a2); a3 = fmaf(l, hi16(q.y), a3);
      }
    } else {
      float m = -3.0e38f;
      for (int k = beg + lane; k < end; k += 64){
        int s = (int)csr[k];
        float e = AS[s] + ad; e = (e > 0.f) ? e : 0.2f*e;
        m = fmaxf(m, e);
      }
      #pragma unroll
      for (int off = 32; off >= 1; off >>= 1) m = fmaxf(m, __shfl_xor(m, off));
      float den = 0.f;
      for (int k = beg + lane; k < end; k += 64){
        int s = (int)csr[k];
        float e = AS[s] + ad; e = (e > 0.f) ? e : 0.2f*e;
        den += __expf(e - m);
      }
      #pragma unroll
      for (int off = 32; off >= 1; off >>= 1) den += __shfl_xor(den, off);
      float inv = 1.0f / (den + 1e-16f);
      for (int j = h; j < deg; j += 2){
        int s = (int)csr[beg + j];
        float e = AS[s] + ad; e = (e > 0.f) ? e : 0.2f*e;
        float al = __expf(e - m) * inv;
        uint2 q = *(const uint2*)&HB[(size_t)s*128 + c4];
        a0 = fmaf(al, lo16(q.x), a0); a1 = fmaf(al, hi16(q.x), a1);
        a2 = fmaf(al, lo16(q.y), a2); a3 = fmaf(al, hi16(q.y), a3);
      }
    }
    a0 += __shfl_xor(a0, 32); a1 += __shfl_xor(a1, 32);
    a2 += __shfl_xor(a2, 32); a3 += __shfl_xor(a3, 32);
  }

  if (lane < 32){
    float v0 = 0.f, v1 = 0.f, v2 = 0.f, v3 = 0.f;
    if (validNode){
      float4 bv = *(const float4*)(bias + c4);
      v0 = fmaxf(a0 + bv.x, 0.f);
      v1 = fmaxf(a1 + bv.y, 0.f);
      v2 = fmaxf(a2 + bv.z, 0.f);
      v3 = fmaxf(a3 + bv.w, 0.f);
      float4 gv = *(const float4*)(gamma_ + c4);
      float4 vv = *(const float4*)(var_   + c4);
      float4 mv = *(const float4*)(mean_  + c4);
      float4 be = *(const float4*)(beta_  + c4);
      v0 = (v0 - mv.x) * (gv.x * rsqrtf(vv.x + 1e-5f)) + be.x;
      v1 = (v1 - mv.y) * (gv.y * rsqrtf(vv.y + 1e-5f)) + be.y;
      v2 = (v2 - mv.z) * (gv.z * rsqrtf(vv.z + 1e-5f)) + be.z;
      v3 = (v3 - mv.w) * (gv.w * rsqrtf(vv.w + 1e-5f)) + be.w;
    }
    float4 o = {v0, v1, v2, v3};
    *(float4*)&xs[w*132 + c4] = o;
    // exact f32 layer-2 logits from this wave's row
    float4 sv = *(const float4*)(ws2 + c4);
    float4 dv = *(const float4*)(wd2 + c4);
    float ps = v0*sv.x + v1*sv.y + v2*sv.z + v3*sv.w;
    float pd = v0*dv.x + v1*dv.y + v2*dv.z + v3*dv.w;
    #pragma unroll
    for (int off = 16; off >= 1; off >>= 1){   // reduce across 32 lanes
      ps += __shfl_xor(ps, off);
      pd += __shfl_xor(pd, off);
    }
    if (lane == 0 && validNode){ AS2[wid] = ps; AD2[wid] = pd; }
  }
  __syncthreads();

  if (w >= 8) return;                    // 8 col-frags, one per wave
  int cf   = w;
  int rloc = lane & 15;
  int q    = lane >> 4;
  int row  = (int)blockIdx.x*16 + rloc;
  fx4 acc = {0.f, 0.f, 0.f, 0.f};
  const u16* wHrow = w2H + (size_t)(cf*16 + rloc)*128;
  const u16* wLrow = w2L + (size_t)(cf*16 + rloc)*128;
  #pragma unroll
  for (int kk = 0; kk < 4; ++kk){
    int kbase = kk*32 + q*8;
    float4 xa = *(const float4*)&xs[rloc*132 + kbase];
    float4 xb = *(const float4*)&xs[rloc*132 + kbase + 4];
    float xv[8] = {xa.x, xa.y, xa.z, xa.w, xb.x, xb.y, xb.z, xb.w};
    bh8 xh, xl;
    #pragma unroll
    for (int i = 0; i < 8; ++i){
      u16 hh = f2b(xv[i]);
      xh[i] = (short)hh;
      xl[i] = (short)f2b(xv[i] - b2f(hh));
    }
    bh8 wh = *(const bh8*)(wHrow + kbase);
    bh8 wl = *(const bh8*)(wLrow + kbase);
    acc = __builtin_amdgcn_mfma_f32_16x16x32_bf16(wh, xh, acc, 0, 0, 0);
    acc = __builtin_amdgcn_mfma_f32_16x16x32_bf16(wl, xh, acc, 0, 0, 0);
    acc = __builtin_amdgcn_mfma_f32_16x16x32_bf16(wh, xl, acc, 0, 0, 0);
  }
  if (row < n){
    uint2 pb;
    pb.x = (u32)f2b(acc[0]) | ((u32)f2b(acc[1]) << 16);
    pb.y = (u32)f2b(acc[2]) | ((u32)f2b(acc[3]) << 16);
    *(uint2*)&HB2[(size_t)row*128 + q*4 + cf*16] = pb;
  }
}

// ---- E: final aggregate (r24/r26-proven, byte-identical) ----
__global__ __launch_bounds__(256)
void r27_aggregate(const u16* __restrict__ HB, const float* __restrict__ AS,
                   const float* __restrict__ AD,
                   const int* __restrict__ offs, const u16* __restrict__ csr,
                   const float* __restrict__ bias,
                   float* __restrict__ outp, int n){
  int wid  = (blockIdx.x*256 + threadIdx.x) >> 6;
  int lane = threadIdx.x & 63;
  if (wid >= n) return;
  int beg = offs[wid], end = offs[wid+1];
  int deg = end - beg;
  float ad = AD[wid];
  int h  = lane >> 5;
  int c4 = (lane & 31) * 4;
  float a0 = 0.f, a1 = 0.f, a2 = 0.f, a3 = 0.f;

  if (deg <= 64){
    int   my_s = 0;
    float my_e = -3.0e38f;
    bool act = (lane < deg);
    if (act){
      my_s = (int)csr[beg + lane];
      float e = AS[my_s] + ad;
      my_e = (e > 0.f) ? e : 0.2f*e;
    }
    float m = my_e;
    #pragma unroll
    for (int off = 32; off >= 1; off >>= 1) m = fmaxf(m, __shfl_xor(m, off));
    float pz = act ? __expf(my_e - m) : 0.f;
    float den = pz;
    #pragma unroll
    for (int off = 32; off >= 1; off >>= 1) den += __shfl_xor(den, off);
    float my_al = pz / (den + 1e-16f);

    int npair = (deg + 1) >> 1;
    int k = 0;
    for (; k + 4 <= npair; k += 4){
      int j0 = 2*k + h, j1 = j0 + 2, j2 = j0 + 4, j3 = j0 + 6;
      int   s0 = __shfl(my_s, j0),  s1 = __shfl(my_s, j1);
      int   s2 = __shfl(my_s, j2),  s3 = __shfl(my_s, j3);
      float l0 = __shfl(my_al, j0), l1 = __shfl(my_al, j1);
      float l2 = __shfl(my_al, j2), l3 = __shfl(my_al, j3);
      uint2 q0 = *(const uint2*)&HB[(size_t)s0*128 + c4];
      uint2 q1 = *(const uint2*)&HB[(size_t)s1*128 + c4];
      uint2 q2 = *(const uint2*)&HB[(size_t)s2*128 + c4];
      uint2 q3 = *(const uint2*)&HB[(size_t)s3*128 + c4];
      a0 = fmaf(l0, lo16(q0.x), a0); a1 = fmaf(l0, hi16(q0.x), a1);
      a2 = fmaf(l0, lo16(q0.y), a2); a3 = fmaf(l0, hi16(q0.y), a3);
      a0 = fmaf(l1, lo16(q1.x), a0); a1 = fmaf(l1, hi16(q1.x), a1);
      a2 = fmaf(l1, lo16(q1.y), a2); a3 = fmaf(l1, hi16(q1.y), a3);
      a0 = fmaf(l2, lo16(q2.x), a0); a1 = fmaf(l2, hi16(q2.x), a1);
      a2 = fmaf(l2, lo16(q2.y), a2); a3 = fmaf(l2, hi16(q2.y), a3);
      a0 = fmaf(l3, lo16(q3.x), a0); a1 = fmaf(l3, hi16(q3.x), a1);
      a2 = fmaf(l3, lo16(q3.y), a2); a3 = fmaf(l3, hi16(q3.y), a3);
    }
    for (; k < npair; ++k){
      int j = 2*k + h;
      int   s = __shfl(my_s, j);
      float l = __shfl(my_al, j);
      uint2 q = *(const uint2*)&HB[(size_t)s*128 + c4];
      a0 = fmaf(l, lo16(q.x), a0); a1 = fmaf(l, hi16(q.x), a1);
      a2 = fmaf(l, lo16(q.y), a2); a3 = fmaf(l, hi16(q.y), a3);
    }
  } else {
    float m = -3.0e38f;
    for (int k = beg + lane; k < end; k += 64){
      int s = (int)csr[k];
      float e = AS[s] + ad; e = (e > 0.f) ? e : 0.2f*e;
      m = fmaxf(m, e);
    }
    #pragma unroll
    for (int off = 32; off >= 1; off >>= 1) m = fmaxf(m, __shfl_xor(m, off));
    float den = 0.f;
    for (int k = beg + lane; k < end; k += 64){
      int s = (int)csr[k];
      float e = AS[s] + ad; e = (e > 0.f) ? e : 0.2f*e;
      den += __expf(e - m);
    }
    #pragma unroll
    for (int off = 32; off >= 1; off >>= 1) den += __shfl_xor(den, off);
    float inv = 1.0f / (den + 1e-16f);
    for (int j = h; j < deg; j += 2){
      int s = (int)csr[beg + j];
      float e = AS[s] + ad; e = (e > 0.f) ? e : 0.2f*e;
      float al = __expf(e - m) * inv;
      uint2 q = *(const uint2*)&HB[(size_t)s*128 + c4];
      a0 = fmaf(al, lo16(q.x), a0); a1 = fmaf(al, hi16(q.x), a1);
      a2 = fmaf(al, lo16(q.y), a2); a3 = fmaf(al, hi16(q.y), a3);
    }
  }

  a0 += __shfl_xor(a0, 32); a1 += __shfl_xor(a1, 32);
  a2 += __shfl_xor(a2, 32); a3 += __shfl_xor(a3, 32);
  if (lane < 32){
    float4 bv = *(const float4*)(bias + c4);
    float4 o;
    o.x = fmaxf(a0 + bv.x, 0.f);
    o.y = fmaxf(a1 + bv.y, 0.f);
    o.z = fmaxf(a2 + bv.z, 0.f);
    o.w = fmaxf(a3 + bv.w, 0.f);
    *(float4*)(outp + (size_t)wid*128 + c4) = o;
  }
}

extern "C" void kernel_launch(void* const* d_in, const int* in_sizes, int n_in,
                              void* d_out, int out_size, void* d_ws, size_t ws_size,
                              hipStream_t stream){
  const float* x   = (const float*)d_in[0];
  const int*   ei  = (const int*)  d_in[1];
  const float* W1  = (const float*)d_in[2];
  const float* as1 = (const float*)d_in[3];
  const float* ad1 = (const float*)d_in[4];
  const float* b1  = (const float*)d_in[5];
  const float* bng = (const float*)d_in[6];
  const float* bnb = (const float*)d_in[7];
  const float* bnm = (const float*)d_in[8];
  const float* bnv = (const float*)d_in[9];
  const float* W2  = (const float*)d_in[10];
  const float* as2 = (const float*)d_in[11];
  const float* ad2 = (const float*)d_in[12];
  const float* b2  = (const float*)d_in[13];
  float* out = (float*)d_out;

  int N  = in_sizes[0] / 128;
  int E  = in_sizes[1] / 2;
  int Ep = E + N;
  if (N <= 0 || E <= 0) return;

  // workspace (~33 MB of 256 MB), 256 B-aligned
  char* base = (char*)d_ws;
  size_t off = 0;
  auto alloc = [&](size_t bytes)->char*{
    off = (off + 255) & ~(size_t)255;
    char* q = base + off; off += bytes; return q;
  };
  float* AS     = (float*)alloc((size_t)N*4);
  float* AD     = (float*)alloc((size_t)N*4);
  float* AS2    = (float*)alloc((size_t)N*4);
  float* AD2    = (float*)alloc((size_t)N*4);
  int*   cnt    = (int*)  alloc((size_t)(N+1)*4);
  int*   offs   = (int*)  alloc((size_t)(N+1)*4);
  int*   pub    = (int*)  alloc(257*4);             // lookback slots + sdone
  u16*   rank   = (u16*)  alloc((size_t)Ep*2);      // within-dst rank per edge
  u16*   csr    = (u16*)  alloc((size_t)Ep*2);      // packed u16 src ids (L2-fit)
  u16*   hb     = (u16*)  alloc((size_t)N*128*2);   // layer-1 bf16 gather operand
  u16*   hb2    = (u16*)  alloc((size_t)N*128*2);   // layer-2 bf16 gather operand
  u16*   w1H    = (u16*)  alloc(128*128*2);         // W^T bf16 hi/lo tables
  u16*   w1L    = (u16*)  alloc(128*128*2);
  u16*   w2H    = (u16*)  alloc(128*128*2);
  u16*   w2L    = (u16*)  alloc(128*128*2);
  float* ws1    = (float*)alloc(128*4);             // W@att vectors (exact logits)
  float* wd1    = (float*)alloc(128*4);
  float* ws2    = (float*)alloc(128*4);
  float* wd2    = (float*)alloc(128*4);

  int n1  = N + 1;
  int sb  = (n1 + 255)/256;             // scan blocks (196 <= 256 required)
  int zb  = (n1 + 257 + 255)/256;       // zero cnt + pub + sdone
  int ebH = (Ep + 2047)/2048;           // hist: 2048 edges per block (8/thread)
  int ebF = (Ep + 1023)/1024;           // fill: 1024 edges per block (4/thread)
  int nW  = (N + 15)/16;                // MFMA gemm: 16 rows / wave
  int gwb = (nW + 3)/4;                 // 4 waves / block
  int fb  = (N + 15)/16;                // fused: 16 nodes / 1024-thr block
  int wb  = (N + 3)/4;                  // aggregate: 4 waves / block

  // A: zero cnt/pub/sdone
  r27_zero<<<zb, 256, 0, stream>>>(cnt, n1, pub);
  // B: histogram (8 edges/thread) + W-prep riders
  r27_hist_prep<<<17 + ebH, 256, 0, stream>>>(ei, E, Ep, cnt, rank,
                                              W1, as1, ad1, W2, as2, ad2,
                                              w1H, w1L, w2H, w2L,
                                              ws1, wd1, ws2, wd2);
  // C: scan + layer-1 MFMA GEMM + fill (fill polls scan-done)
  r27_gemm_scan_fill<<<sb + gwb + ebF, 256, 0, stream>>>(x, w1H, w1L, ws1, wd1,
                                                         hb, AS, AD, N, sb, gwb,
                                                         ei, E, Ep, cnt, n1,
                                                         offs, pub, rank, csr);
  // D: fused agg1 (relu+BN) + layer-2 GEMM -> hb2, AS2, AD2
  r27_fused<<<fb, 1024, 0, stream>>>(hb, AS, AD, offs, csr, b1,
                                     bng, bnb, bnm, bnv,
                                     w2H, w2L, ws2, wd2,
                                     hb2, AS2, AD2, N);
  // E: final aggregate -> relu -> out
  r27_aggregate<<<wb, 256, 0, stream>>>(hb2, AS2, AD2, offs, csr, b2, out, N);
}

// Round 13
// 287.966 us; speedup vs baseline: 1.1138x; 1.1138x over previous
//
// rev r28 — r26 locked in + one audited micro-delta (fill 8 edges/thread,
// mirroring hist's proven batching; halves fill blocks -> shorter tail).
// r27 post-mortem: THIRD structural-merge failure (r22 additive pairing,
// r25 queue TLP-loss, r27 poll-contention: ~780 spinning blocks hammered
// sdone's L2 line, contended with pub lookback, starved the GEMM; fat
// kernel 51+4 -> 100 µs). Firm rule: co-dispatch roles only when mutually
// independent & non-blocking (gemm+fill). Remaining ~79 µs inter-dispatch
// gap would need a cooperative mega-kernel — negative risk-adjusted EV
// after three failed cousins. Aggregates are latency-bound random gathers
// at ~3 TB/s effective cache BW; all width/ILP variants were neutral.
// r24: 297.1, r25: 312.9, r26: 289.7 (best), r27: 320.7.
#include <hip/hip_runtime.h>

typedef unsigned short u16;
typedef unsigned int   u32;
typedef __attribute__((ext_vector_type(8))) short bh8;   // 8 bf16 (4 VGPRs)
typedef __attribute__((ext_vector_type(4))) float fx4;   // MFMA accumulator

#define SCAN_FLAG 0x40000000

__device__ __forceinline__ float b2f(u16 h){ return __uint_as_float(((u32)h) << 16); }
__device__ __forceinline__ u16   f2b(float f){
  u32 u = __float_as_uint(f);
  u32 r = u + 0x7FFFu + ((u >> 16) & 1u);   // round-to-nearest-even
  return (u16)(r >> 16);
}
__device__ __forceinline__ float lo16(u32 w){ return b2f((u16)(w & 0xFFFFu)); }
__device__ __forceinline__ float hi16(u32 w){ return b2f((u16)(w >> 16)); }

// ---- A: zero cnt + pub (pure, ~2 µs) ----
__global__ void r28_zero(int* __restrict__ cnt, int n1, int* __restrict__ pub){
  int g = (int)blockIdx.x*256 + threadIdx.x;
  if (g < n1) cnt[g] = 0;
  else if (g < n1 + 256) pub[g - n1] = 0;
}

// ---- B: W^T bf16 hi/lo tables (blocks 0..15), ws/wd (block 16),
// histogram 8 edges/thread (blocks 17..) — prep rides free under hist.
__global__ void r28_hist_prep(const int* __restrict__ ei, int E, int Ep, int* cnt,
                              u16* __restrict__ rank,
                              const float* __restrict__ W1, const float* __restrict__ as1,
                              const float* __restrict__ ad1,
                              const float* __restrict__ W2, const float* __restrict__ as2,
                              const float* __restrict__ ad2,
                              u16* __restrict__ w1H, u16* __restrict__ w1L,
                              u16* __restrict__ w2H, u16* __restrict__ w2L,
                              float* __restrict__ ws1, float* __restrict__ wd1,
                              float* __restrict__ ws2, float* __restrict__ wd2){
  int b = blockIdx.x;
  int t = threadIdx.x;
  if (b < 16){
    const float* W = (b < 8) ? W1 : W2;
    u16* HT = (b < 8) ? w1H : w2H;
    u16* LT = (b < 8) ? w1L : w2L;
    int n0 = (b & 7) * 16;
    #pragma unroll
    for (int it = 0; it < 8; ++it){
      int idx = it*256 + t;              // 0..2047
      int nn = n0 + (idx >> 7);
      int k = idx & 127;
      float w = W[(size_t)k*128 + nn];
      u16 h = f2b(w);
      HT[(size_t)nn*128 + k] = h;
      LT[(size_t)nn*128 + k] = f2b(w - b2f(h));
    }
    return;
  }
  if (b == 16){
    int which = t >> 6;                  // 0:ws1 1:wd1 2:ws2 3:wd2
    const float* W   = (which < 2) ? W1 : W2;
    const float* att = (which == 0) ? as1 : (which == 1) ? ad1 : (which == 2) ? as2 : ad2;
    float* outv      = (which == 0) ? ws1 : (which == 1) ? wd1 : (which == 2) ? ws2 : wd2;
    int k0 = (t & 63) * 2;
    #pragma unroll
    for (int kk = 0; kk < 2; ++kk){
      int k = k0 + kk;
      float s = 0.f;
      for (int c = 0; c < 128; ++c) s = fmaf(W[(size_t)k*128 + c], att[c], s);
      outv[k] = s;
    }
    return;
  }
  int g0 = (b - 17)*2048 + t;
  #pragma unroll
  for (int i = 0; i < 8; ++i){
    int g = g0 + i*256;
    if (g < Ep){
      int dst = (g < E) ? ei[E + g] : (g - E);
      int r = atomicAdd(&cnt[dst], 1);
      rank[g] = (u16)r;
    }
  }
}

// ---- C: one-dispatch decoupled-lookback exclusive scan  [r22/r26-proven] ----
__global__ __launch_bounds__(256)
void r28_scan(const int* __restrict__ cnt, int n, int* __restrict__ offs,
              int* __restrict__ pub){
  __shared__ int tmp[256];
  __shared__ int red[256];
  int t = threadIdx.x; int b = blockIdx.x; int g = b*256 + t;
  int v = (g < n) ? cnt[g] : 0;
  tmp[t] = v; __syncthreads();
  for (int off = 1; off < 256; off <<= 1){
    int u = (t >= off) ? tmp[t - off] : 0;
    __syncthreads();
    tmp[t] += u;
    __syncthreads();
  }
  int incl = tmp[t];
  if (t == 255) atomicExch(&pub[b], tmp[255] | SCAN_FLAG);
  int val = 0;
  if (t < b){
    int p;
    do { p = atomicAdd(&pub[t], 0); } while (!(p & SCAN_FLAG));
    val = p & ~SCAN_FLAG;
  }
  red[t] = val; __syncthreads();
  for (int off = 128; off >= 1; off >>= 1){
    if (t < off) red[t] += red[t + off];
    __syncthreads();
  }
  int add = red[0];
  if (g < n) offs[g] = add + incl - v;   // exclusive prefix
}

// ---------------- MFMA bf16 GEMM, one wave = 16 rows, LDS-free ---------------
__device__ __forceinline__ void gemm16_wave(
    const float* __restrict__ X, const u16* __restrict__ wH, const u16* __restrict__ wL,
    const float* __restrict__ wsv, const float* __restrict__ wdv,
    u16* __restrict__ HB, float* __restrict__ AS, float* __restrict__ AD,
    int nrows, int w, int lane)
{
  int r0 = w * 16;
  if (r0 >= nrows) return;
  int rloc = lane & 15;
  int q    = lane >> 4;                   // k-chunk 0..3 within a K=32 step
  int myrow = r0 + rloc;
  bool act = (myrow < nrows);
  int rsafe = act ? myrow : (nrows - 1);

  fx4 acc[8] = {};                        // 8 col-frags x 4 f32
  float ds = 0.f, dd = 0.f;

  const u16* wHrow = wH + (size_t)rloc * 128;
  const u16* wLrow = wL + (size_t)rloc * 128;

  #pragma unroll
  for (int kk = 0; kk < 4; ++kk){
    int kbase = kk*32 + q*8;
    const float* xp = X + (size_t)rsafe*128 + kbase;
    float4 xa = *(const float4*)xp;
    float4 xb = *(const float4*)(xp + 4);
    float xv[8] = {xa.x, xa.y, xa.z, xa.w, xb.x, xb.y, xb.z, xb.w};
    if (!act){
      #pragma unroll
      for (int i = 0; i < 8; ++i) xv[i] = 0.f;
    }
    const float* sp = wsv + kbase;
    const float* dp = wdv + kbase;
    bh8 xh, xl;
    #pragma unroll
    for (int i = 0; i < 8; ++i){
      ds = fmaf(xv[i], sp[i], ds);        // exact f32 logit path: X@(W@att)
      dd = fmaf(xv[i], dp[i], dd);
      u16 h = f2b(xv[i]);
      xh[i] = (short)h;
      xl[i] = (short)f2b(xv[i] - b2f(h)); // hi/lo split: ~2^-17 rel error
    }
    #pragma unroll
    for (int cf = 0; cf < 8; ++cf){
      bh8 wh = *(const bh8*)(wHrow + (size_t)cf*2048 + kbase);
      bh8 wl = *(const bh8*)(wLrow + (size_t)cf*2048 + kbase);
      acc[cf] = __builtin_amdgcn_mfma_f32_16x16x32_bf16(wh, xh, acc[cf], 0, 0, 0);
      acc[cf] = __builtin_amdgcn_mfma_f32_16x16x32_bf16(wl, xh, acc[cf], 0, 0, 0);
      acc[cf] = __builtin_amdgcn_mfma_f32_16x16x32_bf16(wh, xl, acc[cf], 0, 0, 0);
    }
  }
  ds += __shfl_xor(ds, 16); ds += __shfl_xor(ds, 32);
  dd += __shfl_xor(dd, 16); dd += __shfl_xor(dd, 32);
  if (act && q == 0){ AS[myrow] = ds; AD[myrow] = dd; }
  if (act){
    u16* hrow = HB + (size_t)myrow*128 + q*4;
    #pragma unroll
    for (int cf = 0; cf < 8; ++cf){
      uint2 pb;
      pb.x = (u32)f2b(acc[cf][0]) | ((u32)f2b(acc[cf][1]) << 16);
      pb.y = (u32)f2b(acc[cf][2]) | ((u32)f2b(acc[cf][3]) << 16);
      *(uint2*)(hrow + cf*16) = pb;       // 4 consecutive bf16 cols, 8B aligned
    }
  }
}

// ---- D: FAT — layer-1 MFMA GEMM first; atomic-free fill behind it.
// Fill now 8 edges/thread (2048-edge blocks, mirrors hist batching).
__global__ __launch_bounds__(256)
void r28_gemm_fill(const float* __restrict__ X,
                   const u16* __restrict__ wH, const u16* __restrict__ wL,
                   const float* __restrict__ wsv, const float* __restrict__ wdv,
                   u16* __restrict__ HB, float* __restrict__ AS, float* __restrict__ AD,
                   int nrows, int gemmBlocks,
                   const int* __restrict__ ei, int E, int Ep,
                   const int* __restrict__ offs, const u16* __restrict__ rank,
                   u16* __restrict__ csr){
  int t = threadIdx.x;
  if ((int)blockIdx.x >= gemmBlocks){
    int g0 = ((int)blockIdx.x - gemmBlocks)*2048 + t;
    #pragma unroll
    for (int i = 0; i < 8; ++i){
      int g = g0 + i*256;
      if (g < Ep){
        int src, dst;
        if (g < E){ src = ei[g]; dst = ei[E + g]; } else { src = g - E; dst = g - E; }
        csr[offs[dst] + (int)rank[g]] = (u16)src;
      }
    }
    return;
  }
  int w = (int)blockIdx.x*4 + (t >> 6);
  gemm16_wave(X, wH, wL, wsv, wdv, HB, AS, AD, nrows, w, t & 63);
}

// ---- E: FUSED agg1 + gemm2 (r24/r26 byte-identical). 16 waves = 16 nodes.
__global__ __launch_bounds__(1024)
void r28_fused(const u16* __restrict__ HB, const float* __restrict__ AS,
               const float* __restrict__ AD,
               const int* __restrict__ offs, const u16* __restrict__ csr,
               const float* __restrict__ bias,
               const float* __restrict__ gamma_, const float* __restrict__ beta_,
               const float* __restrict__ mean_, const float* __restrict__ var_,
               const u16* __restrict__ w2H, const u16* __restrict__ w2L,
               const float* __restrict__ ws2, const float* __restrict__ wd2,
               u16* __restrict__ HB2, float* __restrict__ AS2, float* __restrict__ AD2,
               int n){
  __shared__ float xs[16*132];           // 16 rows, stride 132 (bank-spread)
  int tid  = threadIdx.x;
  int w    = tid >> 6;                   // wave 0..15 = node slot
  int lane = tid & 63;
  int wid  = (int)blockIdx.x*16 + w;
  bool validNode = (wid < n);
  int h  = lane >> 5;
  int c4 = (lane & 31) * 4;
  float a0 = 0.f, a1 = 0.f, a2 = 0.f, a3 = 0.f;

  if (validNode){
    int beg = offs[wid], end = offs[wid+1];
    int deg = end - beg;
    float ad = AD[wid];
    if (deg <= 64){
      int   my_s = 0;
      float my_e = -3.0e38f;
      bool act = (lane < deg);
      if (act){
        my_s = (int)csr[beg + lane];
        float e = AS[my_s] + ad;
        my_e = (e > 0.f) ? e : 0.2f*e;
      }
      float m = my_e;
      #pragma unroll
      for (int off = 32; off >= 1; off >>= 1) m = fmaxf(m, __shfl_xor(m, off));
      float pz = act ? __expf(my_e - m) : 0.f;
      float den = pz;
      #pragma unroll
      for (int off = 32; off >= 1; off >>= 1) den += __shfl_xor(den, off);
      float my_al = pz / (den + 1e-16f);

      int npair = (deg + 1) >> 1;
      int k = 0;
      for (; k + 4 <= npair; k += 4){
        int j0 = 2*k + h, j1 = j0 + 2, j2 = j0 + 4, j3 = j0 + 6;
        int   s0 = __shfl(my_s, j0),  s1 = __shfl(my_s, j1);
        int   s2 = __shfl(my_s, j2),  s3 = __shfl(my_s, j3);
        float l0 = __shfl(my_al, j0), l1 = __shfl(my_al, j1);
        float l2 = __shfl(my_al, j2), l3 = __shfl(my_al, j3);
        uint2 q0 = *(const uint2*)&HB[(size_t)s0*128 + c4];
        uint2 q1 = *(const uint2*)&HB[(size_t)s1*128 + c4];
        uint2 q2 = *(const uint2*)&HB[(size_t)s2*128 + c4];
        uint2 q3 = *(const uint2*)&HB[(size_t)s3*128 + c4];
        a0 = fmaf(l0, lo16(q0.x), a0); a1 = fmaf(l0, hi16(q0.x), a1);
        a2 = fmaf(l0, lo16(q0.y), a2); a3 = fmaf(l0, hi16(q0.y), a3);
        a0 = fmaf(l1, lo16(q1.x), a0); a1 = fmaf(l1, hi16(q1.x), a1);
        a2 = fmaf(l1, lo16(q1.y), a2); a3 = fmaf(l1, hi16(q1.y), a3);
        a0 = fmaf(l2, lo16(q2.x), a0); a1 = fmaf(l2, hi16(q2.x), a1);
        a2 = fmaf(l2, lo16(q2.y), a2); a3 = fmaf(l2, hi16(q2.y), a3);
        a0 = fmaf(l3, lo16(q3.x), a0); a1 = fmaf(l3, hi16(q3.x), a1);
        a2 = fmaf(l3, lo16(q3.y), a2); a3 = fmaf(l3, hi16(q3.y), a3);
      }
      for (; k < npair; ++k){
        int j = 2*k + h;
        int   s = __shfl(my_s, j);
        float l = __shfl(my_al, j);
        uint2 q = *(const uint2*)&HB[(size_t)s*128 + c4];
        a0 = fmaf(l, lo16(q.x), a0); a1 = fmaf(l, hi16(q.x), a1);
        a2 = fmaf(l, lo16(q.y), a2); a3 = fmaf(l, hi16(q.y), a3);
      }
    } else {
      float m = -3.0e38f;
      for (int k = beg + lane; k < end; k += 64){
        int s = (int)csr[k];
        float e = AS[s] + ad; e = (e > 0.f) ? e : 0.2f*e;
        m = fmaxf(m, e);
      }
      #pragma unroll
      for (int off = 32; off >= 1; off >>= 1) m = fmaxf(m, __shfl_xor(m, off));
      float den = 0.f;
      for (int k = beg + lane; k < end; k += 64){
        int s = (int)csr[k];
        float e = AS[s] + ad; e = (e > 0.f) ? e : 0.2f*e;
        den += __expf(e - m);
      }
      #pragma unroll
      for (int off = 32; off >= 1; off >>= 1) den += __shfl_xor(den, off);
      float inv = 1.0f / (den + 1e-16f);
      for (int j = h; j < deg; j += 2){
        int s = (int)csr[beg + j];
        float e = AS[s] + ad; e = (e > 0.f) ? e : 0.2f*e;
        float al = __expf(e - m) * inv;
        uint2 q = *(const uint2*)&HB[(size_t)s*128 + c4];
        a0 = fmaf(al, lo16(q.x), a0); a1 = fmaf(al, hi16(q.x), a1);
        a2 = fmaf(al, lo16(q.y), a2); a3 = fmaf(al, hi16(q.y), a3);
      }
    }
    a0 += __shfl_xor(a0, 32); a1 += __shfl_xor(a1, 32);
    a2 += __shfl_xor(a2, 32); a3 += __shfl_xor(a3, 32);
  }

  if (lane < 32){
    float v0 = 0.f, v1 = 0.f, v2 = 0.f, v3 = 0.f;
    if (validNode){
      float4 bv = *(const float4*)(bias + c4);
      v0 = fmaxf(a0 + bv.x, 0.f);
      v1 = fmaxf(a1 + bv.y, 0.f);
      v2 = fmaxf(a2 + bv.z, 0.f);
      v3 = fmaxf(a3 + bv.w, 0.f);
      float4 gv = *(const float4*)(gamma_ + c4);
      float4 vv = *(const float4*)(var_   + c4);
      float4 mv = *(const float4*)(mean_  + c4);
      float4 be = *(const float4*)(beta_  + c4);
      v0 = (v0 - mv.x) * (gv.x * rsqrtf(vv.x + 1e-5f)) + be.x;
      v1 = (v1 - mv.y) * (gv.y * rsqrtf(vv.y + 1e-5f)) + be.y;
      v2 = (v2 - mv.z) * (gv.z * rsqrtf(vv.z + 1e-5f)) + be.z;
      v3 = (v3 - mv.w) * (gv.w * rsqrtf(vv.w + 1e-5f)) + be.w;
    }
    float4 o = {v0, v1, v2, v3};
    *(float4*)&xs[w*132 + c4] = o;
    // exact f32 layer-2 logits from this wave's row
    float4 sv = *(const float4*)(ws2 + c4);
    float4 dv = *(const float4*)(wd2 + c4);
    float ps = v0*sv.x + v1*sv.y + v2*sv.z + v3*sv.w;
    float pd = v0*dv.x + v1*dv.y + v2*dv.z + v3*dv.w;
    #pragma unroll
    for (int off = 16; off >= 1; off >>= 1){   // reduce across 32 lanes
      ps += __shfl_xor(ps, off);
      pd += __shfl_xor(pd, off);
    }
    if (lane == 0 && validNode){ AS2[wid] = ps; AD2[wid] = pd; }
  }
  __syncthreads();

  if (w >= 8) return;                    // 8 col-frags, one per wave
  int cf   = w;
  int rloc = lane & 15;
  int q    = lane >> 4;
  int row  = (int)blockIdx.x*16 + rloc;
  fx4 acc = {0.f, 0.f, 0.f, 0.f};
  const u16* wHrow = w2H + (size_t)(cf*16 + rloc)*128;
  const u16* wLrow = w2L + (size_t)(cf*16 + rloc)*128;
  #pragma unroll
  for (int kk = 0; kk < 4; ++kk){
    int kbase = kk*32 + q*8;
    float4 xa = *(const float4*)&xs[rloc*132 + kbase];
    float4 xb = *(const float4*)&xs[rloc*132 + kbase + 4];
    float xv[8] = {xa.x, xa.y, xa.z, xa.w, xb.x, xb.y, xb.z, xb.w};
    bh8 xh, xl;
    #pragma unroll
    for (int i = 0; i < 8; ++i){
      u16 hh = f2b(xv[i]);
      xh[i] = (short)hh;
      xl[i] = (short)f2b(xv[i] - b2f(hh));
    }
    bh8 wh = *(const bh8*)(wHrow + kbase);
    bh8 wl = *(const bh8*)(wLrow + kbase);
    acc = __builtin_amdgcn_mfma_f32_16x16x32_bf16(wh, xh, acc, 0, 0, 0);
    acc = __builtin_amdgcn_mfma_f32_16x16x32_bf16(wl, xh, acc, 0, 0, 0);
    acc = __builtin_amdgcn_mfma_f32_16x16x32_bf16(wh, xl, acc, 0, 0, 0);
  }
  if (row < n){
    uint2 pb;
    pb.x = (u32)f2b(acc[0]) | ((u32)f2b(acc[1]) << 16);
    pb.y = (u32)f2b(acc[2]) | ((u32)f2b(acc[3]) << 16);
    *(uint2*)&HB2[(size_t)row*128 + q*4 + cf*16] = pb;
  }
}

// ---- F: final aggregate (r24/r26-proven, byte-identical) ----
__global__ __launch_bounds__(256)
void r28_aggregate(const u16* __restrict__ HB, const float* __restrict__ AS,
                   const float* __restrict__ AD,
                   const int* __restrict__ offs, const u16* __restrict__ csr,
                   const float* __restrict__ bias,
                   float* __restrict__ outp, int n){
  int wid  = (blockIdx.x*256 + threadIdx.x) >> 6;
  int lane = threadIdx.x & 63;
  if (wid >= n) return;
  int beg = offs[wid], end = offs[wid+1];
  int deg = end - beg;
  float ad = AD[wid];
  int h  = lane >> 5;
  int c4 = (lane & 31) * 4;
  float a0 = 0.f, a1 = 0.f, a2 = 0.f, a3 = 0.f;

  if (deg <= 64){
    int   my_s = 0;
    float my_e = -3.0e38f;
    bool act = (lane < deg);
    if (act){
      my_s = (int)csr[beg + lane];
      float e = AS[my_s] + ad;
      my_e = (e > 0.f) ? e : 0.2f*e;
    }
    float m = my_e;
    #pragma unroll
    for (int off = 32; off >= 1; off >>= 1) m = fmaxf(m, __shfl_xor(m, off));
    float pz = act ? __expf(my_e - m) : 0.f;
    float den = pz;
    #pragma unroll
    for (int off = 32; off >= 1; off >>= 1) den += __shfl_xor(den, off);
    float my_al = pz / (den + 1e-16f);

    int npair = (deg + 1) >> 1;
    int k = 0;
    for (; k + 4 <= npair; k += 4){
      int j0 = 2*k + h, j1 = j0 + 2, j2 = j0 + 4, j3 = j0 + 6;
      int   s0 = __shfl(my_s, j0),  s1 = __shfl(my_s, j1);
      int   s2 = __shfl(my_s, j2),  s3 = __shfl(my_s, j3);
      float l0 = __shfl(my_al, j0), l1 = __shfl(my_al, j1);
      float l2 = __shfl(my_al, j2), l3 = __shfl(my_al, j3);
      uint2 q0 = *(const uint2*)&HB[(size_t)s0*128 + c4];
      uint2 q1 = *(const uint2*)&HB[(size_t)s1*128 + c4];
      uint2 q2 = *(const uint2*)&HB[(size_t)s2*128 + c4];
      uint2 q3 = *(const uint2*)&HB[(size_t)s3*128 + c4];
      a0 = fmaf(l0, lo16(q0.x), a0); a1 = fmaf(l0, hi16(q0.x), a1);
      a2 = fmaf(l0, lo16(q0.y), a2); a3 = fmaf(l0, hi16(q0.y), a3);
      a0 = fmaf(l1, lo16(q1.x), a0); a1 = fmaf(l1, hi16(q1.x), a1);
      a2 = fmaf(l1, lo16(q1.y), a2); a3 = fmaf(l1, hi16(q1.y), a3);
      a0 = fmaf(l2, lo16(q2.x), a0); a1 = fmaf(l2, hi16(q2.x), a1);
      a2 = fmaf(l2, lo16(q2.y), a2); a3 = fmaf(l2, hi16(q2.y), a3);
      a0 = fmaf(l3, lo16(q3.x), a0); a1 = fmaf(l3, hi16(q3.x), a1);
      a2 = fmaf(l3, lo16(q3.y), a2); a3 = fmaf(l3, hi16(q3.y), a3);
    }
    for (; k < npair; ++k){
      int j = 2*k + h;
      int   s = __shfl(my_s, j);
      float l = __shfl(my_al, j);
      uint2 q = *(const uint2*)&HB[(size_t)s*128 + c4];
      a0 = fmaf(l, lo16(q.x), a0); a1 = fmaf(l, hi16(q.x), a1);
      a2 = fmaf(l, lo16(q.y), a2); a3 = fmaf(l, hi16(q.y), a3);
    }
  } else {
    float m = -3.0e38f;
    for (int k = beg + lane; k < end; k += 64){
      int s = (int)csr[k];
      float e = AS[s] + ad; e = (e > 0.f) ? e : 0.2f*e;
      m = fmaxf(m, e);
    }
    #pragma unroll
    for (int off = 32; off >= 1; off >>= 1) m = fmaxf(m, __shfl_xor(m, off));
    float den = 0.f;
    for (int k = beg + lane; k < end; k += 64){
      int s = (int)csr[k];
      float e = AS[s] + ad; e = (e > 0.f) ? e : 0.2f*e;
      den += __expf(e - m);
    }
    #pragma unroll
    for (int off = 32; off >= 1; off >>= 1) den += __shfl_xor(den, off);
    float inv = 1.0f / (den + 1e-16f);
    for (int j = h; j < deg; j += 2){
      int s = (int)csr[beg + j];
      float e = AS[s] + ad; e = (e > 0.f) ? e : 0.2f*e;
      float al = __expf(e - m) * inv;
      uint2 q = *(const uint2*)&HB[(size_t)s*128 + c4];
      a0 = fmaf(al, lo16(q.x), a0); a1 = fmaf(al, hi16(q.x), a1);
      a2 = fmaf(al, lo16(q.y), a2); a3 = fmaf(al, hi16(q.y), a3);
    }
  }

  a0 += __shfl_xor(a0, 32); a1 += __shfl_xor(a1, 32);
  a2 += __shfl_xor(a2, 32); a3 += __shfl_xor(a3, 32);
  if (lane < 32){
    float4 bv = *(const float4*)(bias + c4);
    float4 o;
    o.x = fmaxf(a0 + bv.x, 0.f);
    o.y = fmaxf(a1 + bv.y, 0.f);
    o.z = fmaxf(a2 + bv.z, 0.f);
    o.w = fmaxf(a3 + bv.w, 0.f);
    *(float4*)(outp + (size_t)wid*128 + c4) = o;
  }
}

extern "C" void kernel_launch(void* const* d_in, const int* in_sizes, int n_in,
                              void* d_out, int out_size, void* d_ws, size_t ws_size,
                              hipStream_t stream){
  const float* x   = (const float*)d_in[0];
  const int*   ei  = (const int*)  d_in[1];
  const float* W1  = (const float*)d_in[2];
  const float* as1 = (const float*)d_in[3];
  const float* ad1 = (const float*)d_in[4];
  const float* b1  = (const float*)d_in[5];
  const float* bng = (const float*)d_in[6];
  const float* bnb = (const float*)d_in[7];
  const float* bnm = (const float*)d_in[8];
  const float* bnv = (const float*)d_in[9];
  const float* W2  = (const float*)d_in[10];
  const float* as2 = (const float*)d_in[11];
  const float* ad2 = (const float*)d_in[12];
  const float* b2  = (const float*)d_in[13];
  float* out = (float*)d_out;

  int N  = in_sizes[0] / 128;
  int E  = in_sizes[1] / 2;
  int Ep = E + N;
  if (N <= 0 || E <= 0) return;

  // workspace (~33 MB of 256 MB), 256 B-aligned
  char* base = (char*)d_ws;
  size_t off = 0;
  auto alloc = [&](size_t bytes)->char*{
    off = (off + 255) & ~(size_t)255;
    char* q = base + off; off += bytes; return q;
  };
  float* AS     = (float*)alloc((size_t)N*4);
  float* AD     = (float*)alloc((size_t)N*4);
  float* AS2    = (float*)alloc((size_t)N*4);
  float* AD2    = (float*)alloc((size_t)N*4);
  int*   cnt    = (int*)  alloc((size_t)(N+1)*4);
  int*   offs   = (int*)  alloc((size_t)(N+1)*4);
  int*   pub    = (int*)  alloc(256*4);             // lookback publish slots
  u16*   rank   = (u16*)  alloc((size_t)Ep*2);      // within-dst rank per edge
  u16*   csr    = (u16*)  alloc((size_t)Ep*2);      // packed u16 src ids (L2-fit)
  u16*   hb     = (u16*)  alloc((size_t)N*128*2);   // layer-1 bf16 gather operand
  u16*   hb2    = (u16*)  alloc((size_t)N*128*2);   // layer-2 bf16 gather operand
  u16*   w1H    = (u16*)  alloc(128*128*2);         // W^T bf16 hi/lo tables
  u16*   w1L    = (u16*)  alloc(128*128*2);
  u16*   w2H    = (u16*)  alloc(128*128*2);
  u16*   w2L    = (u16*)  alloc(128*128*2);
  float* ws1    = (float*)alloc(128*4);             // W@att vectors (exact logits)
  float* wd1    = (float*)alloc(128*4);
  float* ws2    = (float*)alloc(128*4);
  float* wd2    = (float*)alloc(128*4);

  int n1  = N + 1;
  int sb  = (n1 + 255)/256;             // scan blocks (196 <= 256 required)
  int zb  = (n1 + 256 + 255)/256;       // zero cnt + pub
  int ebH = (Ep + 2047)/2048;           // hist: 2048 edges per block (8/thread)
  int ebF = (Ep + 2047)/2048;           // fill: 2048 edges per block (8/thread)
  int nW  = (N + 15)/16;                // MFMA gemm: 16 rows / wave
  int gwb = (nW + 3)/4;                 // 4 waves / block
  int fb  = (N + 15)/16;                // fused: 16 nodes / 1024-thr block
  int wb  = (N + 3)/4;                  // aggregate: 4 waves / block

  // A: zero cnt/pub
  r28_zero<<<zb, 256, 0, stream>>>(cnt, n1, pub);
  // B: histogram (8 edges/thread) + W-prep riders
  r28_hist_prep<<<17 + ebH, 256, 0, stream>>>(ei, E, Ep, cnt, rank,
                                              W1, as1, ad1, W2, as2, ad2,
                                              w1H, w1L, w2H, w2L,
                                              ws1, wd1, ws2, wd2);
  // C: one-dispatch lookback scan
  r28_scan<<<sb, 256, 0, stream>>>(cnt, n1, offs, pub);
  // D: layer-1 MFMA GEMM + atomic-free fill (8 edges/thread)
  r28_gemm_fill<<<gwb + ebF, 256, 0, stream>>>(x, w1H, w1L, ws1, wd1,
                                               hb, AS, AD, N, gwb,
                                               ei, E, Ep, offs, rank, csr);
  // E: fused agg1 (relu+BN) + layer-2 GEMM -> hb2, AS2, AD2
  r28_fused<<<fb, 1024, 0, stream>>>(hb, AS, AD, offs, csr, b1,
                                     bng, bnb, bnm, bnv,
                                     w2H, w2L, ws2, wd2,
                                     hb2, AS2, AD2, N);
  // F: final aggregate -> relu -> out
  r28_aggregate<<<wb, 256, 0, stream>>>(hb2, AS2, AD2, offs, csr, b2, out, N);
}